// Round 1
// baseline (707.453 us; speedup 1.0000x reference)
//
#include <hip/hip_runtime.h>
#include <hip/hip_bf16.h>

// Shapes
#define M_CELLS 4096
#define N_GENES 4000
#define KP      4032   // 63 * 64, zero-padded K
#define NKT     63     // K tiles of 64
#define N_OUT   12288  // 64 patches * 192 embed
#define EMB     192
#define NPATCH  64

typedef __attribute__((ext_vector_type(8))) short bf16x8_t;
typedef __attribute__((ext_vector_type(8))) unsigned short u16x8_t;
typedef __attribute__((ext_vector_type(4))) float f32x4_t;

__device__ __forceinline__ unsigned short f2bf(float f) {
  __hip_bfloat16 h = __float2bfloat16(f);
  return *reinterpret_cast<unsigned short*>(&h);
}

__device__ __forceinline__ void gll16(const unsigned short* g, unsigned short* l) {
  __builtin_amdgcn_global_load_lds(
      (const __attribute__((address_space(1))) void*)g,
      (__attribute__((address_space(3))) void*)l, 16, 0, 0);
}

// ---------------- prepA: x fp32[4096x4000] -> bf16 A'[4096x4032] (zero-pad K) ----------------
__global__ __launch_bounds__(256) void prepA(const float* __restrict__ x,
                                             unsigned short* __restrict__ A) {
  const int NG = M_CELLS * (KP / 8);  // groups of 8 elems
  for (int g = blockIdx.x * 256 + threadIdx.x; g < NG; g += 2048 * 256) {
    int row = g / (KP / 8);
    int kc  = g - row * (KP / 8);
    int k   = kc * 8;
    u16x8_t v;
    if (k < N_GENES) {  // 4000 % 8 == 0, so a group is fully valid or fully pad
      float4 f0 = *reinterpret_cast<const float4*>(x + (size_t)row * N_GENES + k);
      float4 f1 = *reinterpret_cast<const float4*>(x + (size_t)row * N_GENES + k + 4);
      v[0] = f2bf(f0.x); v[1] = f2bf(f0.y); v[2] = f2bf(f0.z); v[3] = f2bf(f0.w);
      v[4] = f2bf(f1.x); v[5] = f2bf(f1.y); v[6] = f2bf(f1.z); v[7] = f2bf(f1.w);
    } else {
      v = (u16x8_t)0;
    }
    *reinterpret_cast<u16x8_t*>(A + (size_t)row * KP + k) = v;
  }
}

// ---------------- prepB: W fp32[4000x12288] * mask -> bf16 Bt tiled [nt][kt][c=128][k=64] ----
// j' = p*192 + e (output col space), original j = e*64 + p. nt = j'>>7, c = j'&127.
__global__ __launch_bounds__(256) void prepB(const float* __restrict__ W,
                                             const float* __restrict__ mask,
                                             unsigned short* __restrict__ Bt) {
  const int t  = threadIdx.x;
  const int jb = blockIdx.x;   // 0..47 (j blocks of 256)
  const int kt = blockIdx.y;   // 0..62
  const int j  = jb * 256 + t;           // original column
  const int e  = j >> 6;                 // j / 64
  const int p  = j & 63;
  const int jp = p * EMB + e;            // permuted column j'
  const int nt = jp >> 7;
  const int c  = jp & 127;
  const int pw = j / EMB;                // pathway index for mask
  const size_t base = (size_t)(nt * NKT + kt) * 8192 + (size_t)c * 64;
#pragma unroll
  for (int chunk = 0; chunk < 8; ++chunk) {
    u16x8_t v;
#pragma unroll
    for (int u = 0; u < 8; ++u) {
      int kg = kt * 64 + chunk * 8 + u;
      float val = 0.f;
      if (kg < N_GENES)
        val = W[(size_t)kg * N_OUT + j] * mask[kg * NPATCH + pw];
      v[u] = f2bf(val);
    }
    *reinterpret_cast<u16x8_t*>(Bt + base + chunk * 8) = v;
  }
}

// ---------------- main GEMM: C[4096x12288] = A'[4096xKP] x Bt + bias, bf16 MFMA --------------
// 128x128 tile, BK=64, 4 waves (2x2), each wave 64x64 = 4x4 frags of 16x16x32.
__global__ __launch_bounds__(256) void gemm_bf16(const unsigned short* __restrict__ A,
                                                 const unsigned short* __restrict__ Bt,
                                                 const float* __restrict__ bias,
                                                 float* __restrict__ out) {
  __shared__ unsigned short sA[128 * 64];
  __shared__ unsigned short sB[128 * 64];
  const int tid  = threadIdx.x;
  const int lane = tid & 63;
  const int w    = tid >> 6;
  const int wr   = w >> 1;     // wave row (0..1)
  const int wc   = w & 1;      // wave col (0..1)

  // XCD-bijective swizzle: grid = 3072, divisible by 8.
  const int nwg = 32 * 96;
  int bid = blockIdx.x;
  int wg  = (bid & 7) * (nwg >> 3) + (bid >> 3);
  int mt  = wg / 96;
  int nt  = wg - mt * 96;
  const int m0 = mt << 7;
  const int n0 = nt << 7;

  // staging source offsets (elements); dest is linear chunk*16B in LDS
  size_t aOff[4], bOff[4];
#pragma unroll
  for (int i = 0; i < 4; ++i) {
    int chunk = i * 256 + tid;           // 0..1023, 16B chunks of the 16KB tile
    aOff[i] = (size_t)(m0 + (chunk >> 3)) * KP + (chunk & 7) * 8;
    bOff[i] = (size_t)nt * NKT * 8192 + (size_t)chunk * 8;
  }

  f32x4_t acc[4][4] = {};

  for (int kt = 0; kt < NKT; ++kt) {
    __syncthreads();  // previous tile fully consumed
#pragma unroll
    for (int i = 0; i < 4; ++i) {
      int chunk = i * 256 + tid;
      gll16(A + aOff[i] + kt * 64, sA + chunk * 8);
      gll16(Bt + bOff[i] + (size_t)kt * 8192, sB + chunk * 8);
    }
    asm volatile("s_waitcnt vmcnt(0)" ::: "memory");
    __syncthreads();
#pragma unroll
    for (int ks = 0; ks < 2; ++ks) {
      const int kr = ks * 32 + (lane >> 4) * 8;
      bf16x8_t af[4], bf[4];
#pragma unroll
      for (int m = 0; m < 4; ++m)
        af[m] = *reinterpret_cast<const bf16x8_t*>(sA + (wr * 64 + m * 16 + (lane & 15)) * 64 + kr);
#pragma unroll
      for (int n = 0; n < 4; ++n)
        bf[n] = *reinterpret_cast<const bf16x8_t*>(sB + (wc * 64 + n * 16 + (lane & 15)) * 64 + kr);
#pragma unroll
      for (int m = 0; m < 4; ++m)
#pragma unroll
        for (int n = 0; n < 4; ++n)
          acc[m][n] = __builtin_amdgcn_mfma_f32_16x16x32_bf16(af[m], bf[n], acc[m][n], 0, 0, 0);
    }
  }

  // Epilogue: C/D layout col = lane&15, row = (lane>>4)*4 + reg. out flat = cell*12288 + j'.
#pragma unroll
  for (int n = 0; n < 4; ++n) {
    int jc = n0 + wc * 64 + n * 16 + (lane & 15);             // global j'
    float bv = bias[(jc % EMB) * NPATCH + (jc / EMB)];        // b[orig(j')]
#pragma unroll
    for (int m = 0; m < 4; ++m) {
      int row = m0 + wr * 64 + m * 16 + ((lane >> 4) << 2);
      float* o = out + (size_t)row * N_OUT + jc;
#pragma unroll
      for (int r = 0; r < 4; ++r)
        o[(size_t)r * N_OUT] = acc[m][n][r] + bv;
    }
  }
}

// ---------------- fallback (ws too small): simple fp32 LDS-tiled GEMM, correct but slow ------
__global__ __launch_bounds__(256) void fallback_gemm(const float* __restrict__ x,
                                                     const float* __restrict__ mask,
                                                     const float* __restrict__ W,
                                                     const float* __restrict__ b,
                                                     float* __restrict__ out) {
  __shared__ float sX[64 * 33];
  __shared__ float sB[32 * 65];
  const int t  = threadIdx.x;
  const int c0 = blockIdx.x * 64;   // cells
  const int j0 = blockIdx.y * 64;   // j' columns
  const int tr = t >> 4, tc = t & 15;
  float acc[4][4] = {};
  for (int k0 = 0; k0 < N_GENES; k0 += 32) {
    __syncthreads();
#pragma unroll
    for (int i = 0; i < 8; ++i) {
      int f = i * 256 + t;
      int row = f >> 5, kk = f & 31;
      sX[row * 33 + kk] = x[(size_t)(c0 + row) * N_GENES + k0 + kk];
    }
#pragma unroll
    for (int i = 0; i < 8; ++i) {
      int f = i * 256 + t;
      int kk = f >> 6, cl = f & 63;
      int jp = j0 + cl;
      int jorig = (jp % EMB) * NPATCH + jp / EMB;
      sB[kk * 65 + cl] = W[(size_t)(k0 + kk) * N_OUT + jorig] * mask[(k0 + kk) * NPATCH + jorig / EMB];
    }
    __syncthreads();
#pragma unroll
    for (int kk = 0; kk < 32; ++kk) {
      float a[4], bb[4];
#pragma unroll
      for (int r = 0; r < 4; ++r) a[r] = sX[(tr * 4 + r) * 33 + kk];
#pragma unroll
      for (int c = 0; c < 4; ++c) bb[c] = sB[kk * 65 + tc * 4 + c];
#pragma unroll
      for (int r = 0; r < 4; ++r)
#pragma unroll
        for (int c = 0; c < 4; ++c) acc[r][c] += a[r] * bb[c];
    }
  }
#pragma unroll
  for (int r = 0; r < 4; ++r)
#pragma unroll
    for (int c = 0; c < 4; ++c) {
      int jp = j0 + tc * 4 + c;
      int jorig = (jp % EMB) * NPATCH + jp / EMB;
      out[(size_t)(c0 + tr * 4 + r) * N_OUT + jp] = acc[r][c] + b[jorig];
    }
}

extern "C" void kernel_launch(void* const* d_in, const int* in_sizes, int n_in,
                              void* d_out, int out_size, void* d_ws, size_t ws_size,
                              hipStream_t stream) {
  const float* x    = (const float*)d_in[0];
  const float* mask = (const float*)d_in[1];
  const float* W    = (const float*)d_in[2];
  const float* b    = (const float*)d_in[3];
  float* out = (float*)d_out;

  const size_t needA = (size_t)M_CELLS * KP * sizeof(unsigned short);  // 33.0 MB
  const size_t needB = (size_t)N_OUT * KP * sizeof(unsigned short);    // 99.1 MB

  if (ws_size >= needA + needB) {
    unsigned short* Abf = (unsigned short*)d_ws;
    unsigned short* Bt  = (unsigned short*)((char*)d_ws + needA);
    prepA<<<2048, 256, 0, stream>>>(x, Abf);
    prepB<<<dim3(48, 63), 256, 0, stream>>>(W, mask, Bt);
    gemm_bf16<<<32 * 96, 256, 0, stream>>>(Abf, Bt, b, out);
  } else {
    fallback_gemm<<<dim3(64, 192), 256, 0, stream>>>(x, mask, W, b, out);
  }
}

// Round 2
// 699.128 us; speedup vs baseline: 1.0119x; 1.0119x over previous
//
#include <hip/hip_runtime.h>
#include <hip/hip_bf16.h>

// Shapes
#define M_CELLS 4096
#define N_GENES 4000
#define KP      4032   // 63 * 64, zero-padded K
#define NKT     63     // K tiles of 64
#define N_OUT   12288  // 64 patches * 192 embed
#define EMB     192
#define NPATCH  64

#define BM 256
#define BN 256
#define BK 64
#define BTILE (BN * BK)   // 16384 elems per B K-tile

typedef __attribute__((ext_vector_type(8))) short bf16x8_t;
typedef __attribute__((ext_vector_type(8))) unsigned short u16x8_t;
typedef __attribute__((ext_vector_type(4))) float f32x4_t;

__device__ __forceinline__ unsigned short f2bf(float f) {
  __hip_bfloat16 h = __float2bfloat16(f);
  return *reinterpret_cast<unsigned short*>(&h);
}

__device__ __forceinline__ void gll16(const unsigned short* g, unsigned short* l) {
  __builtin_amdgcn_global_load_lds(
      (const __attribute__((address_space(1))) void*)g,
      (__attribute__((address_space(3))) void*)l, 16, 0, 0);
}

// ---------------- prepA: x fp32[4096x4000] -> bf16 A'[4096x4032] (zero-pad K) ----------------
__global__ __launch_bounds__(256) void prepA(const float* __restrict__ x,
                                             unsigned short* __restrict__ A) {
  const int NG = M_CELLS * (KP / 8);
  for (int g = blockIdx.x * 256 + threadIdx.x; g < NG; g += 2048 * 256) {
    int row = g / (KP / 8);
    int kc  = g - row * (KP / 8);
    int k   = kc * 8;
    u16x8_t v;
    if (k < N_GENES) {
      float4 f0 = *reinterpret_cast<const float4*>(x + (size_t)row * N_GENES + k);
      float4 f1 = *reinterpret_cast<const float4*>(x + (size_t)row * N_GENES + k + 4);
      v[0] = f2bf(f0.x); v[1] = f2bf(f0.y); v[2] = f2bf(f0.z); v[3] = f2bf(f0.w);
      v[4] = f2bf(f1.x); v[5] = f2bf(f1.y); v[6] = f2bf(f1.z); v[7] = f2bf(f1.w);
    } else {
      v = (u16x8_t)0;
    }
    *reinterpret_cast<u16x8_t*>(A + (size_t)row * KP + k) = v;
  }
}

// ---------------- prepB: W fp32[4000x12288] * mask -> bf16 Bt tiled [nt][kt][c=256][k=64] ----
// j' = p*192 + e (output col space), original j = e*64 + p. nt = j'>>8, c = j'&255.
__global__ __launch_bounds__(256) void prepB(const float* __restrict__ W,
                                             const float* __restrict__ mask,
                                             unsigned short* __restrict__ Bt) {
  const int t  = threadIdx.x;
  const int jb = blockIdx.x;   // 0..47
  const int kt = blockIdx.y;   // 0..62
  const int j  = jb * 256 + t;
  const int e  = j >> 6;
  const int p  = j & 63;
  const int jp = p * EMB + e;
  const int nt = jp >> 8;
  const int c  = jp & 255;
  const int pw = j / EMB;
  const size_t base = (size_t)(nt * NKT + kt) * BTILE + (size_t)c * 64;
#pragma unroll
  for (int chunk = 0; chunk < 8; ++chunk) {
    u16x8_t v;
#pragma unroll
    for (int u = 0; u < 8; ++u) {
      int kg = kt * 64 + chunk * 8 + u;
      float val = 0.f;
      if (kg < N_GENES)
        val = W[(size_t)kg * N_OUT + j] * mask[kg * NPATCH + pw];
      v[u] = f2bf(val);
    }
    *reinterpret_cast<u16x8_t*>(Bt + base + chunk * 8) = v;
  }
}

// ---------------- main GEMM: 256x256 tile, BK=64, 8 waves, 4-phase pipelined schedule --------
__global__ __launch_bounds__(512, 2) void gemm_bf16(const unsigned short* __restrict__ A,
                                                    const unsigned short* __restrict__ Bt,
                                                    const float* __restrict__ bias,
                                                    float* __restrict__ out) {
  __shared__ unsigned short sA[2][BM * BK];
  __shared__ unsigned short sB[2][BN * BK];

  const int tid  = threadIdx.x;
  const int lane = tid & 63;
  const int wid  = tid >> 6;   // 0..7
  const int wm   = wid >> 2;   // 0..1
  const int wn   = wid & 3;    // 0..3
  const int lr   = lane & 15;
  const int hi   = lane >> 4;  // 0..3

  // XCD-chunked mapping: grid 768 = 8 XCDs x (16 mt x 6 nt_local), mt fastest.
  const int bid = blockIdx.x;
  const int xcd = bid & 7;
  const int l   = bid >> 3;    // 0..95
  const int mt  = l & 15;
  const int ntl = l >> 4;      // 0..5
  const int nt  = xcd * 6 + ntl;
  const int m0  = mt * BM;
  const int n0  = nt * BN;
  const size_t bBase = (size_t)nt * NKT * BTILE;

  f32x4_t acc[8][4] = {};

  // stage K-tile kt into buffer buf. LDS dest linear (wave-uniform base + lane*16B);
  // swizzle applied on the GLOBAL source: slot' = slot ^ (row&7)  (involution).
  auto STAGE = [&](int kt, int buf) {
#pragma unroll
    for (int i = 0; i < 4; ++i) {
      int ch = i * 512 + tid;          // 0..2047 16B chunks
      int row = ch >> 3, sl = ch & 7;
      gll16(A + (size_t)(m0 + row) * KP + kt * BK + ((sl ^ (row & 7)) << 3),
            &sA[buf][ch * 8]);
    }
#pragma unroll
    for (int i = 0; i < 4; ++i) {
      int ch = i * 512 + tid;
      int row = ch >> 3, sl = ch & 7;
      gll16(Bt + bBase + (size_t)kt * BTILE + row * BK + ((sl ^ (row & 7)) << 3),
            &sB[buf][ch * 8]);
    }
  };

  // Prologue: tile0 -> buf0, tile1 -> buf1; wait tile0 (vmcnt(8): 16 issued, 8 oldest done).
  STAGE(0, 0);
  STAGE(1, 1);
  asm volatile("s_waitcnt vmcnt(8)" ::: "memory");
  __builtin_amdgcn_s_barrier();
  __builtin_amdgcn_sched_barrier(0);

  int cbuf = 0;
  bf16x8_t af[4][2], bfr[2][2];

// swizzled fragment read: row-major [256][64] bf16, slot = 16B unit within row
#define FRAG(baseP, row, slot) \
  (*reinterpret_cast<const bf16x8_t*>((baseP) + (row) * BK + ((((slot) ^ ((row) & 7))) << 3)))

#define READ_A(MH) \
  _Pragma("unroll") for (int m_ = 0; m_ < 4; ++m_) \
  _Pragma("unroll") for (int ks_ = 0; ks_ < 2; ++ks_) \
    af[m_][ks_] = FRAG(curA, wm * 128 + (MH) * 64 + m_ * 16 + lr, ks_ * 4 + hi);

#define READ_B(NP) \
  _Pragma("unroll") for (int n_ = 0; n_ < 2; ++n_) \
  _Pragma("unroll") for (int ks_ = 0; ks_ < 2; ++ks_) \
    bfr[n_][ks_] = FRAG(curB, wn * 64 + (NP) * 32 + n_ * 16 + lr, ks_ * 4 + hi);

#define MFMA_Q(MH, NP) \
  __builtin_amdgcn_s_setprio(1); \
  _Pragma("unroll") for (int m_ = 0; m_ < 4; ++m_) \
  _Pragma("unroll") for (int n_ = 0; n_ < 2; ++n_) \
  _Pragma("unroll") for (int ks_ = 0; ks_ < 2; ++ks_) \
    acc[(MH) * 4 + m_][(NP) * 2 + n_] = __builtin_amdgcn_mfma_f32_16x16x32_bf16( \
        af[m_][ks_], bfr[n_][ks_], acc[(MH) * 4 + m_][(NP) * 2 + n_], 0, 0, 0); \
  __builtin_amdgcn_s_setprio(0);

#define BAR_IN() \
  __builtin_amdgcn_s_barrier(); \
  asm volatile("s_waitcnt lgkmcnt(0)" ::: "memory"); \
  __builtin_amdgcn_sched_barrier(0);

#define BAR_OUT() \
  __builtin_amdgcn_s_barrier(); \
  __builtin_amdgcn_sched_barrier(0);

  for (int t = 0; t < NKT; ++t) {
    const unsigned short* curA = sA[cbuf];
    const unsigned short* curB = sB[cbuf];

    // 4 phases, quadrant snake: (m0-3,n0-1) (m0-3,n2-3) (m4-7,n2-3) (m4-7,n0-1)
    READ_A(0); READ_B(0); BAR_IN(); MFMA_Q(0, 0); BAR_OUT();
    READ_B(1);            BAR_IN(); MFMA_Q(0, 1); BAR_OUT();
    READ_A(1);            BAR_IN(); MFMA_Q(1, 1); BAR_OUT();
    READ_B(0);            BAR_IN(); MFMA_Q(1, 0); BAR_OUT();

    // Tail: all waves past the last read of buf[cbuf] -> safe to restage it.
    if (t + 1 < NKT) {
      if (t + 2 < NKT) {
        STAGE(t + 2, cbuf);
        asm volatile("s_waitcnt vmcnt(8)" ::: "memory");  // tile t+1 landed
      } else {
        asm volatile("s_waitcnt vmcnt(0)" ::: "memory");  // last tile: drain
      }
      __builtin_amdgcn_s_barrier();
      __builtin_amdgcn_sched_barrier(0);
      cbuf ^= 1;
    }
  }

  // Epilogue: C/D layout col=lane&15, row=(lane>>4)*4+reg. out flat = cell*12288 + j'.
#pragma unroll
  for (int n = 0; n < 4; ++n) {
    int jc = n0 + wn * 64 + n * 16 + lr;
    float bv = bias[(jc % EMB) * NPATCH + (jc / EMB)];
#pragma unroll
    for (int m = 0; m < 8; ++m) {
      int row = m0 + wm * 128 + m * 16 + hi * 4;
      float* o = out + (size_t)row * N_OUT + jc;
#pragma unroll
      for (int r = 0; r < 4; ++r)
        o[(size_t)r * N_OUT] = acc[m][n][r] + bv;
    }
  }
}

// ---------------- fallback (ws too small): simple fp32 LDS-tiled GEMM, correct but slow ------
__global__ __launch_bounds__(256) void fallback_gemm(const float* __restrict__ x,
                                                     const float* __restrict__ mask,
                                                     const float* __restrict__ W,
                                                     const float* __restrict__ b,
                                                     float* __restrict__ out) {
  __shared__ float sX[64 * 33];
  __shared__ float sB2[32 * 65];
  const int t  = threadIdx.x;
  const int c0 = blockIdx.x * 64;
  const int j0 = blockIdx.y * 64;
  const int tr = t >> 4, tc = t & 15;
  float acc[4][4] = {};
  for (int k0 = 0; k0 < N_GENES; k0 += 32) {
    __syncthreads();
#pragma unroll
    for (int i = 0; i < 8; ++i) {
      int f = i * 256 + t;
      int row = f >> 5, kk = f & 31;
      sX[row * 33 + kk] = x[(size_t)(c0 + row) * N_GENES + k0 + kk];
    }
#pragma unroll
    for (int i = 0; i < 8; ++i) {
      int f = i * 256 + t;
      int kk = f >> 6, cl = f & 63;
      int jp = j0 + cl;
      int jorig = (jp % EMB) * NPATCH + jp / EMB;
      sB2[kk * 65 + cl] = W[(size_t)(k0 + kk) * N_OUT + jorig] * mask[(k0 + kk) * NPATCH + jorig / EMB];
    }
    __syncthreads();
#pragma unroll
    for (int kk = 0; kk < 32; ++kk) {
      float a[4], bb[4];
#pragma unroll
      for (int r = 0; r < 4; ++r) a[r] = sX[(tr * 4 + r) * 33 + kk];
#pragma unroll
      for (int c = 0; c < 4; ++c) bb[c] = sB2[kk * 65 + tc * 4 + c];
#pragma unroll
      for (int r = 0; r < 4; ++r)
#pragma unroll
        for (int c = 0; c < 4; ++c) acc[r][c] += a[r] * bb[c];
    }
  }
#pragma unroll
  for (int r = 0; r < 4; ++r)
#pragma unroll
    for (int c = 0; c < 4; ++c) {
      int jp = j0 + tc * 4 + c;
      int jorig = (jp % EMB) * NPATCH + jp / EMB;
      out[(size_t)(c0 + tr * 4 + r) * N_OUT + jp] = acc[r][c] + b[jorig];
    }
}

extern "C" void kernel_launch(void* const* d_in, const int* in_sizes, int n_in,
                              void* d_out, int out_size, void* d_ws, size_t ws_size,
                              hipStream_t stream) {
  const float* x    = (const float*)d_in[0];
  const float* mask = (const float*)d_in[1];
  const float* W    = (const float*)d_in[2];
  const float* b    = (const float*)d_in[3];
  float* out = (float*)d_out;

  const size_t needA = (size_t)M_CELLS * KP * sizeof(unsigned short);  // 33.0 MB
  const size_t needB = (size_t)N_OUT * KP * sizeof(unsigned short);    // 99.1 MB

  if (ws_size >= needA + needB) {
    unsigned short* Abf = (unsigned short*)d_ws;
    unsigned short* Bt  = (unsigned short*)((char*)d_ws + needA);
    prepA<<<2048, 256, 0, stream>>>(x, Abf);
    prepB<<<dim3(48, 63), 256, 0, stream>>>(W, mask, Bt);
    gemm_bf16<<<768, 512, 0, stream>>>(Abf, Bt, b, out);
  } else {
    fallback_gemm<<<dim3(64, 192), 256, 0, stream>>>(x, mask, W, b, out);
  }
}

// Round 3
// 489.517 us; speedup vs baseline: 1.4452x; 1.4282x over previous
//
#include <hip/hip_runtime.h>
#include <hip/hip_bf16.h>

// Shapes
#define M_CELLS 4000000 / 1000 * 1024 / 1000  // (unused sanity) — real values below
#undef M_CELLS
#define M_CELLS 4096
#define N_GENES 4000
#define KP      4032   // 63 * 64, zero-padded K
#define NKT     63     // K tiles of 64
#define N_OUT   12288  // 64 patches * 192 embed
#define EMB     192
#define NPATCH  64

#define BM 256
#define BN 256
#define BK 64
#define BTILE (BN * BK)   // 16384 elems per B K-tile

typedef __attribute__((ext_vector_type(8))) short bf16x8_t;
typedef __attribute__((ext_vector_type(8))) unsigned short u16x8_t;
typedef __attribute__((ext_vector_type(4))) float f32x4_t;

__device__ __forceinline__ unsigned short f2bf(float f) {
  __hip_bfloat16 h = __float2bfloat16(f);
  return *reinterpret_cast<unsigned short*>(&h);
}

__device__ __forceinline__ void gll16(const unsigned short* g, unsigned short* l) {
  __builtin_amdgcn_global_load_lds(
      (const __attribute__((address_space(1))) void*)g,
      (__attribute__((address_space(3))) void*)l, 16, 0, 0);
}

// ---------------- prepA: x fp32[4096x4000] -> bf16 A'[4096x4032] (zero-pad K) ----------------
__global__ __launch_bounds__(256) void prepA(const float* __restrict__ x,
                                             unsigned short* __restrict__ A) {
  const int NG = M_CELLS * (KP / 8);
  for (int g = blockIdx.x * 256 + threadIdx.x; g < NG; g += 2048 * 256) {
    int row = g / (KP / 8);
    int kc  = g - row * (KP / 8);
    int k   = kc * 8;
    u16x8_t v;
    if (k < N_GENES) {
      float4 f0 = *reinterpret_cast<const float4*>(x + (size_t)row * N_GENES + k);
      float4 f1 = *reinterpret_cast<const float4*>(x + (size_t)row * N_GENES + k + 4);
      v[0] = f2bf(f0.x); v[1] = f2bf(f0.y); v[2] = f2bf(f0.z); v[3] = f2bf(f0.w);
      v[4] = f2bf(f1.x); v[5] = f2bf(f1.y); v[6] = f2bf(f1.z); v[7] = f2bf(f1.w);
    } else {
      v = (u16x8_t)0;
    }
    *reinterpret_cast<u16x8_t*>(A + (size_t)row * KP + k) = v;
  }
}

// ---------------- prepB2: W*mask -> bf16 Bt tiled [nt][kt][c=256][k=64], LDS re-order --------
// jp = p*192 + e; block covers j = jb*256.. (e = 4jb..4jb+3, p = 0..63), writes 512B runs.
__global__ __launch_bounds__(256) void prepB2(const float* __restrict__ W,
                                              const float* __restrict__ mask,
                                              unsigned short* __restrict__ Bt) {
  __shared__ unsigned short sT[256 * 72];  // [j_local][k], padded row = 72 elems
  const int t  = threadIdx.x;
  const int jb = blockIdx.x;     // 0..47
  const int kt = blockIdx.y;     // 0..62
  const int j  = jb * 256 + t;
  const int pw = j / EMB;
#pragma unroll
  for (int ch = 0; ch < 8; ++ch) {
    u16x8_t v;
#pragma unroll
    for (int u = 0; u < 8; ++u) {
      int kg = kt * 64 + ch * 8 + u;
      float val = 0.f;
      if (kg < N_GENES) val = W[(size_t)kg * N_OUT + j] * mask[kg * NPATCH + pw];
      v[u] = f2bf(val);
    }
    *reinterpret_cast<u16x8_t*>(&sT[t * 72 + ch * 8]) = v;
  }
  __syncthreads();
#pragma unroll
  for (int it = 0; it < 8; ++it) {
    int f  = it * 256 + t;
    int p  = f >> 5, u = f & 31;
    int el = u >> 3, k0 = (u & 7) * 8;
    u16x8_t v = *reinterpret_cast<const u16x8_t*>(&sT[(el * 64 + p) * 72 + k0]);
    int jp0 = p * EMB + jb * 4;
    int nt  = jp0 >> 8, c = jp0 & 255;
    *reinterpret_cast<u16x8_t*>(&Bt[(size_t)(nt * NKT + kt) * BTILE + (size_t)c * 64 + u * 8]) = v;
  }
}

// ---------------- main GEMM: 256x256, BK=64 split in 2 K-halves, true 8-phase schedule -------
// LDS: sA/sB[2buf][2kh][256 rows][32 k] swizzled slot' = slot ^ ((row>>1)&3). 128 KiB total.
#define ABASE(buf, ks) (((buf) * 2 + (ks)) * 8192)
#define BBASE(buf, ks) (32768 + ((buf) * 2 + (ks)) * 8192)

__global__ __launch_bounds__(512, 2) void gemm_bf16(const unsigned short* __restrict__ A,
                                                    const unsigned short* __restrict__ Bt,
                                                    const float* __restrict__ bias,
                                                    float* __restrict__ out) {
  __shared__ unsigned short lds[65536];  // 128 KiB

  const int tid  = threadIdx.x;
  const int lane = tid & 63;
  const int wid  = tid >> 6;   // 0..7
  const int wm   = wid >> 2;   // 0..1
  const int wn   = wid & 3;    // 0..3
  const int lr   = lane & 15;
  const int hi   = lane >> 4;  // 0..3
  const int swz  = (lr >> 1) & 3;

  // XCD-chunked mapping: grid 768 = 8 XCDs x (16 mt x 6 nt_local).
  const int bid = blockIdx.x;
  const int xcd = bid & 7;
  const int l   = bid >> 3;
  const int mt  = l & 15;
  const int nt  = xcd * 6 + (l >> 4);
  const int m0  = mt * BM;
  const int n0  = nt * BN;

  // fragment LDS element offsets (within a [256][32] chunk)
  const int aoff = (wm * 128 + lr) * 32 + ((hi ^ swz) << 3);
  const int boff = (wn * 64 + lr) * 32 + ((hi ^ swz) << 3);

  // staging source base pointers (per-thread); chunk unit u0 = tid, u1 = tid+512
  const int srow = tid >> 2;
  const int ssl  = ((tid & 3) ^ ((tid >> 3) & 3)) << 3;  // swizzled 16B slot * 8 elems
  const unsigned short* aS0 = A + (size_t)(m0 + srow) * KP + ssl;
  const unsigned short* aS1 = aS0 + (size_t)128 * KP;
  const unsigned short* bS0 = Bt + (size_t)nt * NKT * BTILE + (size_t)srow * 64 + ssl;
  const unsigned short* bS1 = bS0 + 8192;  // +128 rows

#define STAGE_A(kt, kh, buf) { \
    gll16(aS0 + (kt) * 64 + (kh) * 32, &lds[ABASE(buf, kh) + tid * 8]); \
    gll16(aS1 + (kt) * 64 + (kh) * 32, &lds[ABASE(buf, kh) + 4096 + tid * 8]); }
#define STAGE_B(kt, kh, buf) { \
    gll16(bS0 + (size_t)(kt) * BTILE + (kh) * 32, &lds[BBASE(buf, kh) + tid * 8]); \
    gll16(bS1 + (size_t)(kt) * BTILE + (kh) * 32, &lds[BBASE(buf, kh) + 4096 + tid * 8]); }

#define READ_AF(buf, ks) \
    _Pragma("unroll") for (int m_ = 0; m_ < 8; ++m_) \
      af[m_] = *reinterpret_cast<const bf16x8_t*>(&lds[ABASE(buf, ks) + aoff + m_ * 512]);
#define READ_B2(buf, ks, nh) { \
    bfr[0] = *reinterpret_cast<const bf16x8_t*>(&lds[BBASE(buf, ks) + boff + (nh) * 1024]); \
    bfr[1] = *reinterpret_cast<const bf16x8_t*>(&lds[BBASE(buf, ks) + boff + (nh) * 1024 + 512]); }

#define MFMA16(nh) \
    __builtin_amdgcn_s_setprio(1); \
    _Pragma("unroll") for (int m_ = 0; m_ < 8; ++m_) { \
      acc[m_][(nh) * 2 + 0] = __builtin_amdgcn_mfma_f32_16x16x32_bf16(af[m_], bfr[0], acc[m_][(nh) * 2 + 0], 0, 0, 0); \
      acc[m_][(nh) * 2 + 1] = __builtin_amdgcn_mfma_f32_16x16x32_bf16(af[m_], bfr[1], acc[m_][(nh) * 2 + 1], 0, 0, 0); } \
    __builtin_amdgcn_s_setprio(0);

#define PH_OPEN() \
    __builtin_amdgcn_s_barrier(); \
    asm volatile("s_waitcnt lgkmcnt(0)" ::: "memory"); \
    __builtin_amdgcn_sched_barrier(0);
#define PH_CLOSE() \
    __builtin_amdgcn_s_barrier(); \
    __builtin_amdgcn_sched_barrier(0);
#define PH_CLOSE_VM(N) \
    asm volatile("s_waitcnt vmcnt(" #N ")" ::: "memory"); \
    __builtin_amdgcn_s_barrier(); \
    __builtin_amdgcn_sched_barrier(0);

  f32x4_t acc[8][4] = {};
  bf16x8_t af[8], bfr[2];

  // Prologue: t0 kh0/kh1 -> buf0, t1 kh0 -> buf1  (12 loads); wait first 8 (buf0 complete).
  STAGE_A(0, 0, 0); STAGE_B(0, 0, 0);
  STAGE_A(0, 1, 0); STAGE_B(0, 1, 0);
  STAGE_A(1, 0, 1); STAGE_B(1, 0, 1);
  asm volatile("s_waitcnt vmcnt(4)" ::: "memory");
  __builtin_amdgcn_s_barrier();
  __builtin_amdgcn_sched_barrier(0);

  for (int i = 0; i < 31; ++i) {
    const int ta = 2 * i, tb = ta + 1, tc = ta + 2;
    const int td = (tb + 2 <= 62) ? tb + 2 : 62;  // clamped dummy on last iter

    // P1: compute(buf0,ks0,n01); stage A-kh1(tb)->buf1ks1   [freed prev P8]
    READ_AF(0, 0); READ_B2(0, 0, 0);
    STAGE_A(tb, 1, 1);
    PH_OPEN(); MFMA16(0); PH_CLOSE();
    // P2: compute(buf0,ks0,n23); stage B-kh1(tb)->buf1ks1
    READ_B2(0, 0, 1);
    STAGE_B(tb, 1, 1);
    PH_OPEN(); MFMA16(1); PH_CLOSE_VM(8);   // ensures buf0ks1 (prev P5/P6) landed
    // P3: compute(buf0,ks1,n01); stage A-kh0(tc)->buf0ks0   [freed at P2]
    READ_AF(0, 1); READ_B2(0, 1, 0);
    STAGE_A(tc, 0, 0);
    PH_OPEN(); MFMA16(0); PH_CLOSE();
    // P4: compute(buf0,ks1,n23); stage B-kh0(tc)->buf0ks0
    READ_B2(0, 1, 1);
    STAGE_B(tc, 0, 0);
    PH_OPEN(); MFMA16(1); PH_CLOSE_VM(8);   // ensures buf1ks0 (prev P7/P8) landed
    // P5: compute(buf1,ks0,n01); stage A-kh1(tc)->buf0ks1   [freed at P4]
    READ_AF(1, 0); READ_B2(1, 0, 0);
    STAGE_A(tc, 1, 0);
    PH_OPEN(); MFMA16(0); PH_CLOSE();
    // P6: compute(buf1,ks0,n23); stage B-kh1(tc)->buf0ks1
    READ_B2(1, 0, 1);
    STAGE_B(tc, 1, 0);
    PH_OPEN(); MFMA16(1); PH_CLOSE_VM(8);   // ensures buf1ks1 (P1/P2) landed
    // P7: compute(buf1,ks1,n01); stage A-kh0(td)->buf1ks0   [freed at P6]
    READ_AF(1, 1); READ_B2(1, 1, 0);
    STAGE_A(td, 0, 1);
    PH_OPEN(); MFMA16(0); PH_CLOSE();
    // P8: compute(buf1,ks1,n23); stage B-kh0(td)->buf1ks0
    READ_B2(1, 1, 1);
    STAGE_B(td, 0, 1);
    PH_OPEN(); MFMA16(1); PH_CLOSE_VM(8);   // ensures buf0ks0 (P3/P4) landed
  }

  // Tail: tile 62 in buf0 (kh0 staged iter30 P3/P4 [landed], kh1 at P5/P6).
  READ_AF(0, 0); READ_B2(0, 0, 0);
  PH_OPEN(); MFMA16(0); PH_CLOSE();
  READ_B2(0, 0, 1);
  PH_OPEN(); MFMA16(1); PH_CLOSE_VM(4);     // ensures buf0ks1 (iter30 P5/P6) landed
  READ_AF(0, 1); READ_B2(0, 1, 0);
  PH_OPEN(); MFMA16(0); PH_CLOSE();
  READ_B2(0, 1, 1);
  PH_OPEN(); MFMA16(1);
  asm volatile("s_waitcnt vmcnt(0)" ::: "memory");
  __builtin_amdgcn_s_barrier();

  // Epilogue: C/D layout col=lane&15, row=(lane>>4)*4+reg. out flat = cell*12288 + j'.
#pragma unroll
  for (int n = 0; n < 4; ++n) {
    int jc = n0 + wn * 64 + n * 16 + lr;
    float bv = bias[(jc % EMB) * NPATCH + (jc / EMB)];
#pragma unroll
    for (int m = 0; m < 8; ++m) {
      int row = m0 + wm * 128 + m * 16 + hi * 4;
      float* o = out + (size_t)row * N_OUT + jc;
#pragma unroll
      for (int r = 0; r < 4; ++r)
        o[(size_t)r * N_OUT] = acc[m][n][r] + bv;
    }
  }
}

// ---------------- fallback (ws too small): simple fp32 LDS-tiled GEMM, correct but slow ------
__global__ __launch_bounds__(256) void fallback_gemm(const float* __restrict__ x,
                                                     const float* __restrict__ mask,
                                                     const float* __restrict__ W,
                                                     const float* __restrict__ b,
                                                     float* __restrict__ out) {
  __shared__ float sX[64 * 33];
  __shared__ float sB2[32 * 65];
  const int t  = threadIdx.x;
  const int c0 = blockIdx.x * 64;
  const int j0 = blockIdx.y * 64;
  const int tr = t >> 4, tc = t & 15;
  float acc[4][4] = {};
  for (int k0 = 0; k0 < N_GENES; k0 += 32) {
    __syncthreads();
#pragma unroll
    for (int i = 0; i < 8; ++i) {
      int f = i * 256 + t;
      int row = f >> 5, kk = f & 31;
      sX[row * 33 + kk] = x[(size_t)(c0 + row) * N_GENES + k0 + kk];
    }
#pragma unroll
    for (int i = 0; i < 8; ++i) {
      int f = i * 256 + t;
      int kk = f >> 6, cl = f & 63;
      int jp = j0 + cl;
      int jorig = (jp % EMB) * NPATCH + jp / EMB;
      sB2[kk * 65 + cl] = W[(size_t)(k0 + kk) * N_OUT + jorig] * mask[(k0 + kk) * NPATCH + jorig / EMB];
    }
    __syncthreads();
#pragma unroll
    for (int kk = 0; kk < 32; ++kk) {
      float a[4], bb[4];
#pragma unroll
      for (int r = 0; r < 4; ++r) a[r] = sX[(tr * 4 + r) * 33 + kk];
#pragma unroll
      for (int c = 0; c < 4; ++c) bb[c] = sB2[kk * 65 + tc * 4 + c];
#pragma unroll
      for (int r = 0; r < 4; ++r)
#pragma unroll
        for (int c = 0; c < 4; ++c) acc[r][c] += a[r] * bb[c];
    }
  }
#pragma unroll
  for (int r = 0; r < 4; ++r)
#pragma unroll
    for (int c = 0; c < 4; ++c) {
      int jp = j0 + tc * 4 + c;
      int jorig = (jp % EMB) * NPATCH + jp / EMB;
      out[(size_t)(c0 + tr * 4 + r) * N_OUT + jp] = acc[r][c] + b[jorig];
    }
}

extern "C" void kernel_launch(void* const* d_in, const int* in_sizes, int n_in,
                              void* d_out, int out_size, void* d_ws, size_t ws_size,
                              hipStream_t stream) {
  const float* x    = (const float*)d_in[0];
  const float* mask = (const float*)d_in[1];
  const float* W    = (const float*)d_in[2];
  const float* b    = (const float*)d_in[3];
  float* out = (float*)d_out;

  const size_t needA = (size_t)M_CELLS * KP * sizeof(unsigned short);  // 33.0 MB
  const size_t needB = (size_t)N_OUT * KP * sizeof(unsigned short);    // 99.1 MB

  if (ws_size >= needA + needB) {
    unsigned short* Abf = (unsigned short*)d_ws;
    unsigned short* Bt  = (unsigned short*)((char*)d_ws + needA);
    prepA<<<2048, 256, 0, stream>>>(x, Abf);
    prepB2<<<dim3(48, 63), 256, 0, stream>>>(W, mask, Bt);
    gemm_bf16<<<768, 512, 0, stream>>>(Abf, Bt, b, out);
  } else {
    fallback_gemm<<<dim3(64, 192), 256, 0, stream>>>(x, mask, W, b, out);
  }
}